// Round 6
// baseline (257.442 us; speedup 1.0000x reference)
//
#include <hip/hip_runtime.h>

// Fused attention with masked-key compaction, 7 dispatches. R14: eliminate the
// Q-GEMM algebraically. Softmax is shift-invariant per row, so
//   QK^T = x(Wq^T Wk)xc^T + 1·d^T + (terms constant over k, which cancel)
// with M=Wq^T·Wk (1024^2), d_k = xc_k·(Wk^T bq). Pipeline:
//  L1 prep:   cast x,W->f16; mask scan; transpose Wq,Wk (f16 WqT/WkT);
//             w = Wk^T·bq (f32); zero M32.
//  L2 mgather: 256 M-partial blocks (128^2 tile x K=256 chunk, f32 atomicAdd
//             into M32) + 2048 gather blocks (xc + dvec = (xc·w)/32).
//  L3 mconv:  M32 -> Mh f16.
//  L4 kvt:    Kc' = xc·M^T (275 tiles) + Vt = Wv xc^T + bv (275) -> T<=1024
//             SINGLE ROUND (R13 lesson: slots = 4/CU x 256 = 1024; old
//             qkvt T~1152 forced 2 rounds = 59us; now ~30us).
//  L5 s128:   S = (xh·Kc'^T)/32 + dvec[col] (body's col-bias path), 550 tiles.
//  L6 softmax, L7 pv128: unchanged.
// R8 lesson: launch_bounds 2nd arg MUST be 4 on the 128-body (5 spills acc).
// R9/R10 lesson: deep pipelines regress at low occupancy; keep 2-barrier body.
// R12 lesson: NO extra addressing in the K-loop (64 VGPR = zero headroom);
// all new logic lives in separate small kernels.
// GEMM core: BK=64, global_load_lds w=16, XOR-swizzled LDS (0 conflicts, R2).

typedef _Float16 f16;
typedef _Float16 f16x4 __attribute__((ext_vector_type(4)));
typedef _Float16 f16x8 __attribute__((ext_vector_type(8)));
typedef float f32x4 __attribute__((ext_vector_type(4)));

#define LB256 __launch_bounds__(256)

__device__ __forceinline__ void gld16(const void* gp, void* lp) {
  __builtin_amdgcn_global_load_lds(
      (__attribute__((address_space(1))) void*)(gp),
      (__attribute__((address_space(3))) void*)(lp),
      16, 0, 0);
}

// ---------------------------------------------------------------- 128x128 GEMM body
template <typename OutT>
__device__ __forceinline__ void gemm_body(
    f16* As, f16* Bs,
    const f16* __restrict__ A, int lda, const f16* __restrict__ B, int ldb,
    OutT* __restrict__ C, int ldc,
    const float* __restrict__ bias1, const float* __restrict__ bias2, int nb1,
    int bias_row, float scale, int K, int m0, int n0) {
  const int tid = threadIdx.x;
  const int w = tid >> 6, l = tid & 63;
  const int wm = (w >> 1) * 64, wn = (w & 1) * 64;
  const int quad = l >> 4, lo = l & 15;
  const int rl = l >> 3;
  const int scol = ((l & 7) ^ rl) * 8;
  const int swz = (quad ^ (lo & 3)) * 8;
  const int ks0 = ((lo >> 2) & 1) * 32;

  f32x4 acc[4][4] = {};
  for (int kk = 0; kk < K; kk += 64) {
#pragma unroll
    for (int r = 0; r < 4; ++r) {
      const int c8 = r * 4 + w;
      const int row = c8 * 8 + rl;
      gld16(A + (long)(m0 + row) * lda + kk + scol, &As[c8 * 512]);
      gld16(B + (long)(n0 + row) * ldb + kk + scol, &Bs[c8 * 512]);
    }
    __syncthreads();
#pragma unroll
    for (int ks = 0; ks < 2; ++ks) {
      const int kso = ks ? (32 - ks0) : ks0;
      f16x8 af[4], bf[4];
#pragma unroll
      for (int i = 0; i < 4; ++i)
        af[i] = *(const f16x8*)&As[(wm + i * 16 + lo) * 64 + swz + kso];
#pragma unroll
      for (int j = 0; j < 4; ++j)
        bf[j] = *(const f16x8*)&Bs[(wn + j * 16 + lo) * 64 + swz + kso];
#pragma unroll
      for (int i = 0; i < 4; ++i)
#pragma unroll
        for (int j = 0; j < 4; ++j)
          acc[i][j] = __builtin_amdgcn_mfma_f32_16x16x32_f16(af[i], bf[j],
                                                             acc[i][j], 0, 0, 0);
    }
    __syncthreads();
  }
#pragma unroll
  for (int i = 0; i < 4; ++i) {
    const int rowb = m0 + wm + i * 16 + quad * 4;
#pragma unroll
    for (int j = 0; j < 4; ++j) {
      const int col = n0 + wn + j * 16 + lo;
      float bc = 0.f;
      if (bias1 && !bias_row) bc = (col < nb1) ? bias1[col] : bias2[col - nb1];
#pragma unroll
      for (int r = 0; r < 4; ++r) {
        float bv = bias_row ? bias1[rowb + r] : bc;
        C[(long)(rowb + r) * ldc + col] = (OutT)(acc[i][j][r] * scale + bv);
      }
    }
  }
}

// ------------------------------------------ 128x128 partial-K body, atomic f32
__device__ __forceinline__ void gemm_mpart(
    f16* As, f16* Bs, const f16* __restrict__ A, const f16* __restrict__ B,
    float* __restrict__ C32, int m0, int n0, int kk0) {
  const int tid = threadIdx.x;
  const int w = tid >> 6, l = tid & 63;
  const int wm = (w >> 1) * 64, wn = (w & 1) * 64;
  const int quad = l >> 4, lo = l & 15;
  const int rl = l >> 3;
  const int scol = ((l & 7) ^ rl) * 8;
  const int swz = (quad ^ (lo & 3)) * 8;
  const int ks0 = ((lo >> 2) & 1) * 32;

  f32x4 acc[4][4] = {};
  for (int kk = kk0; kk < kk0 + 256; kk += 64) {
#pragma unroll
    for (int r = 0; r < 4; ++r) {
      const int c8 = r * 4 + w;
      const int row = c8 * 8 + rl;
      gld16(A + (long)(m0 + row) * 1024 + kk + scol, &As[c8 * 512]);
      gld16(B + (long)(n0 + row) * 1024 + kk + scol, &Bs[c8 * 512]);
    }
    __syncthreads();
#pragma unroll
    for (int ks = 0; ks < 2; ++ks) {
      const int kso = ks ? (32 - ks0) : ks0;
      f16x8 af[4], bf[4];
#pragma unroll
      for (int i = 0; i < 4; ++i)
        af[i] = *(const f16x8*)&As[(wm + i * 16 + lo) * 64 + swz + kso];
#pragma unroll
      for (int j = 0; j < 4; ++j)
        bf[j] = *(const f16x8*)&Bs[(wn + j * 16 + lo) * 64 + swz + kso];
#pragma unroll
      for (int i = 0; i < 4; ++i)
#pragma unroll
        for (int j = 0; j < 4; ++j)
          acc[i][j] = __builtin_amdgcn_mfma_f32_16x16x32_f16(af[i], bf[j],
                                                             acc[i][j], 0, 0, 0);
    }
    __syncthreads();
  }
#pragma unroll
  for (int i = 0; i < 4; ++i) {
    const int rowb = m0 + wm + i * 16 + quad * 4;
#pragma unroll
    for (int j = 0; j < 4; ++j) {
      const int col = n0 + wn + j * 16 + lo;
#pragma unroll
      for (int r = 0; r < 4; ++r)
        atomicAdd(&C32[(long)(rowb + r) * 1024 + col], acc[i][j][r]);
    }
  }
}

// ---------------------------------------------------------------- L1 prep
// [0,11264) cast x/W -> f16 | [11264,11268) mask scan | [11268,11780)
// transpose Wq,Wk -> WqT,WkT f16 | [11780,11812) w = Wk^T bq | [11812,11876) zero M32
__global__ LB256 void prep(const float* __restrict__ x, const float* __restrict__ wq,
                           const float* __restrict__ wk, const float* __restrict__ wv,
                           const void* __restrict__ maskp, const float* __restrict__ bq,
                           f16* __restrict__ xh, f16* __restrict__ wh,
                           f16* __restrict__ wqt, f16* __restrict__ wkt,
                           float* __restrict__ m32, float* __restrict__ wbuf,
                           int* __restrict__ sel, int* __restrict__ counts,
                           int* __restrict__ npad) {
  const int blk = blockIdx.x;
  const int t = threadIdx.x;
  if (blk < 11264) {
    long i = ((long)blk * 256 + t) * 4;
    const float* src;
    f16* dst;
    if (i < 8388608L) {
      src = x + i;
      dst = xh + i;
    } else {
      long j = i - 8388608L;
      int which = (int)(j >> 20);
      const float* ws = which == 0 ? wq : (which == 1 ? wk : wv);
      src = ws + (j & 1048575L);
      dst = wh + j;
    }
    float4 v = *(const float4*)src;
    f16x4 o;
    o[0] = (f16)v.x; o[1] = (f16)v.y; o[2] = (f16)v.z; o[3] = (f16)v.w;
    *(f16x4*)dst = o;
  } else if (blk < 11268) {
    const int b = blk - 11264;
    __shared__ int bad;
    __shared__ int s[256];
    if (t == 0) bad = 0;
    __syncthreads();
    const int* mi = (const int*)maskp;
    int loc = 0;
    for (int i = t; i < 2048; i += 256)
      if ((unsigned)mi[i] > 1u) loc = 1;  // byte-packed bools look like big ints
    if (loc) atomicOr(&bad, 1);
    __syncthreads();
    const bool bytemode = bad != 0;
    int m[8];
    if (bytemode) {
      const unsigned char* p = (const unsigned char*)maskp + b * 2048 + t * 8;
#pragma unroll
      for (int e = 0; e < 8; ++e) m[e] = p[e] != 0;
    } else {
      const int* p = mi + b * 2048 + t * 8;
#pragma unroll
      for (int e = 0; e < 8; ++e) m[e] = p[e] != 0;
    }
    int local = 0;
#pragma unroll
    for (int e = 0; e < 8; ++e) local += m[e];
    s[t] = local;
    __syncthreads();
    for (int off = 1; off < 256; off <<= 1) {
      int v = (t >= off) ? s[t - off] : 0;
      __syncthreads();
      s[t] += v;
      __syncthreads();
    }
    int offp = s[t] - local;
#pragma unroll
    for (int e = 0; e < 8; ++e)
      if (m[e]) sel[b * 2048 + offp++] = t * 8 + e;
    if (t == 0) {
      counts[b] = s[255];
      npad[b] = ((s[255] + 127) >> 7) << 7;
    }
  } else if (blk < 11780) {
    // transpose: dst[d][e] = src[e][d], 64x64 tiles
    const int u = blk - 11268;
    const float* src = (u >> 8) ? wk : wq;
    f16* dst = (u >> 8) ? wkt : wqt;
    const int tile = u & 255, tr = tile >> 4, tc = tile & 15;
    __shared__ f16 lt[64][68];
    const int r = t >> 2, cg = t & 3;
#pragma unroll
    for (int uu = 0; uu < 4; ++uu) {
      float4 v = *(const float4*)&src[(long)(tr * 64 + r) * 1024 + tc * 64 +
                                      cg * 16 + uu * 4];
      lt[r][cg * 16 + uu * 4 + 0] = (f16)v.x;
      lt[r][cg * 16 + uu * 4 + 1] = (f16)v.y;
      lt[r][cg * 16 + uu * 4 + 2] = (f16)v.z;
      lt[r][cg * 16 + uu * 4 + 3] = (f16)v.w;
    }
    __syncthreads();
    const int c = t >> 2, rg = t & 3;
    f16x8 o0, o1;
#pragma unroll
    for (int e = 0; e < 8; ++e) {
      o0[e] = lt[rg * 16 + e][c];
      o1[e] = lt[rg * 16 + 8 + e][c];
    }
    f16* drow = dst + (long)(tc * 64 + c) * 1024 + tr * 64 + rg * 16;
    *(f16x8*)drow = o0;
    *(f16x8*)(drow + 8) = o1;
  } else if (blk < 11812) {
    // w[i] = sum_e Wk[e][i] * bq[e]
    const int i0 = (blk - 11780) * 32;
    const int il = t & 31, part = t >> 5;
    float s = 0.f;
    for (int e = part; e < 1024; e += 8) s += wk[(long)e * 1024 + i0 + il] * bq[e];
    __shared__ float red[256];
    red[t] = s;
    __syncthreads();
    if (t < 32) {
      float a = 0.f;
#pragma unroll
      for (int pp = 0; pp < 8; ++pp) a += red[pp * 32 + t];
      wbuf[i0 + t] = a;
    }
  } else {
    // zero M32: 64 blocks x 16384 f32
    float4* base = (float4*)m32 + (long)(blk - 11812) * 4096;
    const float4 z = {0.f, 0.f, 0.f, 0.f};
#pragma unroll
    for (int uu = 0; uu < 16; ++uu) base[uu * 256 + t] = z;
  }
}

// ---------------------------------------------------------------- L2 mgather
// [0,256): M partials: M[d][d'] += sum_{e in chunk} WqT[d][e]*WkT[d'][e]
// [256,2304): gather xc rows via sel + dvec = (xc.w)/32
__global__ LB256 void mgather(const f16* __restrict__ xh, const int* __restrict__ sel,
                              const int* __restrict__ counts,
                              const int* __restrict__ npad, f16* __restrict__ xc,
                              const f16* __restrict__ wqt, const f16* __restrict__ wkt,
                              float* __restrict__ m32, const float* __restrict__ wbuf,
                              float* __restrict__ dvec) {
  __shared__ __align__(16) f16 As[128 * 64];
  __shared__ __align__(16) f16 Bs[128 * 64];
  const int t = threadIdx.x;
  if (blockIdx.x < 256) {
    const int p = blockIdx.x >> 6, tile = blockIdx.x & 63;
    gemm_mpart(As, Bs, wqt, wkt, m32, (tile & 7) * 128, (tile >> 3) * 128,
               p * 256);
    return;
  }
  const int g = blockIdx.x - 256;
  const int b = g >> 9, gx = g & 511;
  const int np = npad[b], cnt = counts[b];
  float* red = (float*)As;
#pragma unroll
  for (int i = 0; i < 4; ++i) {
    const int sp = gx * 4 + i;
    if (sp >= np) continue;  // block-uniform
    f16* dst = xc + ((long)b * 2048 + sp) * 1024;
    float dot = 0.f;
    if (sp >= cnt) {
      *(f16x4*)(dst + t * 4) = (f16x4){0, 0, 0, 0};
    } else {
      const f16* src = xh + ((long)b * 2048 + sel[b * 2048 + sp]) * 1024;
      f16x4 v = *(const f16x4*)(src + t * 4);
      *(f16x4*)(dst + t * 4) = v;
      dot = (float)v[0] * wbuf[t * 4] + (float)v[1] * wbuf[t * 4 + 1] +
            (float)v[2] * wbuf[t * 4 + 2] + (float)v[3] * wbuf[t * 4 + 3];
    }
#pragma unroll
    for (int off = 32; off > 0; off >>= 1) dot += __shfl_xor(dot, off, 64);
    if ((t & 63) == 0) red[t >> 6] = dot;
    __syncthreads();
    if (t == 0)
      dvec[b * 2048 + sp] = (red[0] + red[1] + red[2] + red[3]) * 0.03125f;
    __syncthreads();
  }
}

// ---------------------------------------------------------------- L3 mconv
__global__ LB256 void mconv(const float* __restrict__ m32, f16* __restrict__ mh) {
  const long base = (long)blockIdx.x * 4096 + threadIdx.x * 16;
#pragma unroll
  for (int uu = 0; uu < 2; ++uu) {
    float4 a = *(const float4*)&m32[base + uu * 8];
    float4 c = *(const float4*)&m32[base + uu * 8 + 4];
    f16x8 o;
    o[0] = (f16)a.x; o[1] = (f16)a.y; o[2] = (f16)a.z; o[3] = (f16)a.w;
    o[4] = (f16)c.x; o[5] = (f16)c.y; o[6] = (f16)c.z; o[7] = (f16)c.w;
    *(f16x8*)&mh[base + uu * 8] = o;
  }
}

// ---------------------------------------------------------------- L4 Kc' + Vt
// Kc' = xc·M^T (npad x 1024): r row-tiles x 8 col-tiles, id = n*MTp + r.
// Vt = Wv xc^T + bv (1024 x npad): id = baseV + m*MTp + r.
// T = 16*MTp <= 1024 even when nothing is masked -> SINGLE ROUND.
__global__ __launch_bounds__(256, 4) void kvt_gemm(
    const f16* __restrict__ xc, const f16* __restrict__ Wh,
    const f16* __restrict__ Mh, f16* __restrict__ Kc, f16* __restrict__ Vt,
    const float* __restrict__ bv, const int* __restrict__ npad) {
  __shared__ __align__(16) f16 As[128 * 64];
  __shared__ __align__(16) f16 Bs[128 * 64];
  int cum[5];
  cum[0] = 0;
#pragma unroll
  for (int b = 0; b < 4; ++b) cum[b + 1] = cum[b] + (npad[b] >> 7);
  const int rowsK = cum[4];
  const int MTp = (rowsK + 7) & ~7;
  const int baseV = 8 * MTp;
  const int T = 16 * MTp;

  for (int tile = blockIdx.x; tile < T; tile += gridDim.x) {
    if (tile < baseV) {
      const int n = tile / MTp, r = tile % MTp;
      if (r >= rowsK) continue;
      int b = 0;
      while (r >= cum[b + 1]) ++b;
      const int m = r - cum[b];
      gemm_body<f16>(As, Bs, xc + (long)b * 2097152, 1024, Mh, 1024,
                     Kc + (long)b * 2097152, 1024, nullptr, nullptr, 0, 0, 1.0f,
                     1024, m * 128, n * 128);
    } else {
      const int u = tile - baseV;
      const int m = u / MTp, r = u % MTp;
      if (r >= rowsK) continue;
      int b = 0;
      while (r >= cum[b + 1]) ++b;
      const int n = r - cum[b];
      gemm_body<f16>(As, Bs, Wh + 2097152, 1024, xc + (long)b * 2097152, 1024,
                     Vt + (long)b * 2097152, 2048, bv, bv, 0, 1, 1.0f, 1024,
                     m * 128, n * 128);
    }
  }
}

// ---------------------------------------------------------------- L5 S GEMM
// S = (xh·Kc'^T)*(1/32) + dvec[col]  (dvec pre-scaled by 1/32)
__global__ __launch_bounds__(256, 4) void s_gemm128(
    const f16* __restrict__ xh, const f16* __restrict__ Kc, f16* __restrict__ Sbuf,
    const float* __restrict__ dvec, const int* __restrict__ npad) {
  __shared__ __align__(16) f16 As[128 * 64];
  __shared__ __align__(16) f16 Bs[128 * 64];
  int cum[5];
  cum[0] = 0;
#pragma unroll
  for (int b = 0; b < 4; ++b) cum[b + 1] = cum[b] + (npad[b] >> 7);
  const int rowsN = cum[4];
  const int Np = (rowsN + 7) & ~7;
  const int T = 16 * Np;

  for (int tile = blockIdx.x; tile < T; tile += gridDim.x) {
    const int m = tile / Np, rn = tile % Np;
    if (rn >= rowsN) continue;
    int b = 0;
    while (rn >= cum[b + 1]) ++b;
    const int n = rn - cum[b];
    gemm_body<f16>(As, Bs, xh + (long)b * 2097152, 1024,
                   Kc + (long)b * 2097152, 1024, Sbuf + (long)b * 4194304, 2048,
                   dvec + b * 2048, dvec + b * 2048, 1 << 30, 0, 0.03125f, 1024,
                   m * 128, n * 128);
  }
}

// ---------------------------------------------------------------- L6 softmax
__global__ LB256 void softmax_w(f16* __restrict__ S, const int* __restrict__ counts,
                                const int* __restrict__ npad) {
  const int wv = threadIdx.x >> 6, l = threadIdx.x & 63;
  const long r = (long)blockIdx.x * 4 + wv;
  const int b = (int)(r >> 11);
  const int nv = counts[b], np = npad[b];
  f16* row = S + r * 2048;

  float v[4][8];
  bool have[4];
  float mx = -3.0e38f;
#pragma unroll
  for (int g = 0; g < 4; ++g) {
    const int idx = (g * 64 + l) * 8;
    have[g] = idx < np;
    if (have[g]) {
      f16x8 sv = *(const f16x8*)(row + idx);
#pragma unroll
      for (int e = 0; e < 8; ++e) {
        float s = (idx + e < nv) ? (float)sv[e] : -3.0e38f;
        v[g][e] = s;
        mx = fmaxf(mx, s);
      }
    } else {
#pragma unroll
      for (int e = 0; e < 8; ++e) v[g][e] = -3.0e38f;
    }
  }
#pragma unroll
  for (int off = 32; off > 0; off >>= 1) mx = fmaxf(mx, __shfl_xor(mx, off, 64));

  float sum = 0.f;
  float ev[4][8];
#pragma unroll
  for (int g = 0; g < 4; ++g)
#pragma unroll
    for (int e = 0; e < 8; ++e) {
      float t = (v[g][e] <= -1.0e38f) ? 0.f : __expf(v[g][e] - mx);
      ev[g][e] = t;
      sum += t;
    }
#pragma unroll
  for (int off = 32; off > 0; off >>= 1) sum += __shfl_xor(sum, off, 64);
  const float inv = 1.f / sum;
#pragma unroll
  for (int g = 0; g < 4; ++g) {
    if (!have[g]) continue;
    const int idx = (g * 64 + l) * 8;
    f16x8 ov;
#pragma unroll
    for (int e = 0; e < 8; ++e) ov[e] = (f16)(ev[g][e] * inv);
    *(f16x8*)(row + idx) = ov;
  }
}

// ---------------------------------------------------------------- L7 PV GEMM
__global__ __launch_bounds__(256, 4) void pv_gemm128(
    const f16* __restrict__ Sbuf, const f16* __restrict__ Vt,
    float* __restrict__ out, const int* __restrict__ npad) {
  __shared__ __align__(16) f16 As[128 * 64];
  __shared__ __align__(16) f16 Bs[128 * 64];
  const int tile = blockIdx.x;
  const int n = tile >> 6, rm = tile & 63, b = rm >> 4, m = rm & 15;
  gemm_body<float>(As, Bs, Sbuf + (long)b * 4194304, 2048,
                   Vt + (long)b * 2097152, 2048, out + (long)b * 2097152,
                   1024, nullptr, nullptr, 0, 0, 1.0f, npad[b], m * 128,
                   n * 128);
}

// ---------------------------------------------------------------- launch
extern "C" void kernel_launch(void* const* d_in, const int* in_sizes, int n_in,
                              void* d_out, int out_size, void* d_ws, size_t ws_size,
                              hipStream_t stream) {
  const float* x = (const float*)d_in[0];
  const void* mask = d_in[1];
  const float* Wq = (const float*)d_in[2];
  const float* bq = (const float*)d_in[3];
  const float* Wk = (const float*)d_in[4];
  const float* bk = (const float*)d_in[5];
  const float* Wv = (const float*)d_in[6];
  const float* bv = (const float*)d_in[7];
  float* out = (float*)d_out;
  (void)bk;  // cancels in softmax (constant over keys... per-query), see header

  // Workspace map (f16 units), ~117.5MB of the proven 118MB.
  f16* xh = (f16*)d_ws;            // 16MB
  f16* xc = xh + 8388608;          // 16MB
  f16* Wh = xc + 8388608;          // 6MB [Wq|Wk|Wv]
  f16* WqT = Wh + 3145728;         // 2MB
  f16* WkT = WqT + 1048576;        // 2MB
  f16* Mh = WkT + 1048576;         // 2MB
  f16* Kc = Mh + 1048576;          // 16MB
  f16* Vt = Kc + 8388608;          // 16MB
  f16* Sbuf = Vt + 8388608;        // 32MB
  float* M32 = (float*)(Sbuf + 16777216);  // 4MB
  float* wbuf = M32 + 1048576;     // 4KB
  float* dvec = wbuf + 1024;       // 32KB
  int* sel = (int*)(dvec + 8192);
  int* counts = sel + 8192;
  int* npad = counts + 4;

  prep<<<11876, 256, 0, stream>>>(x, Wq, Wk, Wv, mask, bq, xh, Wh, WqT, WkT,
                                  M32, wbuf, sel, counts, npad);
  mgather<<<2304, 256, 0, stream>>>(xh, sel, counts, npad, xc, WqT, WkT, M32,
                                    wbuf, dvec);
  mconv<<<256, 256, 0, stream>>>(M32, Mh);
  kvt_gemm<<<1024, 256, 0, stream>>>(xc, Wh, Mh, Kc, Vt, bv, npad);
  s_gemm128<<<1024, 256, 0, stream>>>(xh, Kc, Sbuf, dvec, npad);
  softmax_w<<<2048, 256, 0, stream>>>(Sbuf, counts, npad);
  pv_gemm128<<<512, 256, 0, stream>>>(Sbuf, Vt, out, npad);
}

// Round 7
// 224.573 us; speedup vs baseline: 1.1464x; 1.1464x over previous
//
#include <hip/hip_runtime.h>

// Fused attention with masked-key compaction, 6 dispatches. R15 = R11 (proven
// 221.5us) + prep-cast rewrite. R14 post-mortem: the algebraic Q-elimination
// cost +36us net (mgather/mconv overheads) -> reverted. But its profile
// surfaced prep = 54us @ 13% HBM BW, VALUBusy 2% -- a latency-bound cast
// (1 float4/thread, 11k tiny blocks, zero ILP). R15 prep: grid-stride cast,
// 2048 blocks x 256 thr x 6 independent float4/thread (96B in flight/thread).
// Expected ~13-17us (BW-bound).
// R8 lesson: launch_bounds 2nd arg MUST be 4 on the 128-body (5 spills acc).
// R9/R10 lesson: deep pipelines regress at low occupancy (1 blk/CU exposes
// every stall; K=1024 can't amortize 8-phase prologues). Keep 2-barrier body.
// R12 lesson: NO extra addressing in the GEMM K-loop (64 VGPR = no headroom).
// R13 lesson: tail-packing via smaller tiles loses more to re-fetch than it
// gains; slots = 4/CU x 256 = 1024 regardless of grid size.
//  L1 prep:    grid-stride cast x,W -> f16 (2048 blks) + mask scan (4 blks)
//  L2 gather:  xc[b][s'] = xh[b][sel[s']] (pad rows zeroed)
//  L3 qkvt:    {Q(512), K(8*MTp), Vt(8*MTp)} XCD-grouped, G=1024 @4/CU
//  L4 s128:    S = (Q Kc^T)/32, 128x128 body, Kc-panel-grouped, G=1024
//  L5 softmax: wave-per-row
//  L6 pv128:   O = P @ Vt^T (K=npad), 128x128 body, Sbuf-panel-grouped, G=512
// GEMM core: BK=64, global_load_lds w=16, XOR-swizzled LDS (0 conflicts, R2).

typedef _Float16 f16;
typedef _Float16 f16x4 __attribute__((ext_vector_type(4)));
typedef _Float16 f16x8 __attribute__((ext_vector_type(8)));
typedef float f32x4 __attribute__((ext_vector_type(4)));

#define LB256 __launch_bounds__(256)

__device__ __forceinline__ void gld16(const void* gp, void* lp) {
  __builtin_amdgcn_global_load_lds(
      (__attribute__((address_space(1))) void*)(gp),
      (__attribute__((address_space(3))) void*)(lp),
      16, 0, 0);
}

// ---------------------------------------------------------------- 128x128 GEMM body
template <typename OutT>
__device__ __forceinline__ void gemm_body(
    f16* As, f16* Bs,
    const f16* __restrict__ A, int lda, const f16* __restrict__ B, int ldb,
    OutT* __restrict__ C, int ldc,
    const float* __restrict__ bias1, const float* __restrict__ bias2, int nb1,
    int bias_row, float scale, int K, int m0, int n0) {
  const int tid = threadIdx.x;
  const int w = tid >> 6, l = tid & 63;
  const int wm = (w >> 1) * 64, wn = (w & 1) * 64;
  const int quad = l >> 4, lo = l & 15;
  const int rl = l >> 3;
  const int scol = ((l & 7) ^ rl) * 8;
  const int swz = (quad ^ (lo & 3)) * 8;
  const int ks0 = ((lo >> 2) & 1) * 32;

  f32x4 acc[4][4] = {};
  for (int kk = 0; kk < K; kk += 64) {
#pragma unroll
    for (int r = 0; r < 4; ++r) {
      const int c8 = r * 4 + w;
      const int row = c8 * 8 + rl;
      gld16(A + (long)(m0 + row) * lda + kk + scol, &As[c8 * 512]);
      gld16(B + (long)(n0 + row) * ldb + kk + scol, &Bs[c8 * 512]);
    }
    __syncthreads();
#pragma unroll
    for (int ks = 0; ks < 2; ++ks) {
      const int kso = ks ? (32 - ks0) : ks0;
      f16x8 af[4], bf[4];
#pragma unroll
      for (int i = 0; i < 4; ++i)
        af[i] = *(const f16x8*)&As[(wm + i * 16 + lo) * 64 + swz + kso];
#pragma unroll
      for (int j = 0; j < 4; ++j)
        bf[j] = *(const f16x8*)&Bs[(wn + j * 16 + lo) * 64 + swz + kso];
#pragma unroll
      for (int i = 0; i < 4; ++i)
#pragma unroll
        for (int j = 0; j < 4; ++j)
          acc[i][j] = __builtin_amdgcn_mfma_f32_16x16x32_f16(af[i], bf[j],
                                                             acc[i][j], 0, 0, 0);
    }
    __syncthreads();
  }
#pragma unroll
  for (int i = 0; i < 4; ++i) {
    const int rowb = m0 + wm + i * 16 + quad * 4;
#pragma unroll
    for (int j = 0; j < 4; ++j) {
      const int col = n0 + wn + j * 16 + lo;
      float bc = 0.f;
      if (bias1 && !bias_row) bc = (col < nb1) ? bias1[col] : bias2[col - nb1];
#pragma unroll
      for (int r = 0; r < 4; ++r) {
        float bv = bias_row ? bias1[rowb + r] : bc;
        C[(long)(rowb + r) * ldc + col] = (OutT)(acc[i][j][r] * scale + bv);
      }
    }
  }
}

// ---------------------------------------------------------------- L1 prep
// [0,2048): grid-stride cast of x (8M f32) + Wq|Wk|Wv (3M f32) -> f16.
//   2883584 float4s over 524288 threads = 5.5 -> 6 guarded, unrolled slots;
//   6 independent 16B loads in flight per thread (latency-hiding ILP).
// [2048,2052): per-batch mask scan (sel/counts/npad).
__global__ LB256 void prep(const float* __restrict__ x, const float* __restrict__ wq,
                           const float* __restrict__ wk, const float* __restrict__ wv,
                           const void* __restrict__ maskp, f16* __restrict__ xh,
                           f16* __restrict__ wh, int* __restrict__ sel,
                           int* __restrict__ counts, int* __restrict__ npad) {
  const int blk = blockIdx.x;
  const int t = threadIdx.x;
  if (blk < 2048) {
    const long u0 = (long)blk * 256 + t;
    const long STRIDE = 2048L * 256;
#pragma unroll
    for (int j = 0; j < 6; ++j) {
      const long u = u0 + j * STRIDE;
      if (u >= 2883584L) continue;
      const long i = u * 4;
      const float* src;
      f16* dst;
      if (i < 8388608L) {
        src = x + i;
        dst = xh + i;
      } else {
        long jj = i - 8388608L;
        int which = (int)(jj >> 20);
        const float* ws = which == 0 ? wq : (which == 1 ? wk : wv);
        src = ws + (jj & 1048575L);
        dst = wh + jj;
      }
      float4 v = *(const float4*)src;
      f16x4 o;
      o[0] = (f16)v.x; o[1] = (f16)v.y; o[2] = (f16)v.z; o[3] = (f16)v.w;
      *(f16x4*)dst = o;
    }
  } else {
    const int b = blk - 2048;
    __shared__ int bad;
    __shared__ int s[256];
    if (t == 0) bad = 0;
    __syncthreads();
    const int* mi = (const int*)maskp;
    int loc = 0;
    for (int i = t; i < 2048; i += 256)
      if ((unsigned)mi[i] > 1u) loc = 1;  // byte-packed bools look like big ints
    if (loc) atomicOr(&bad, 1);
    __syncthreads();
    const bool bytemode = bad != 0;
    int m[8];
    if (bytemode) {
      const unsigned char* p = (const unsigned char*)maskp + b * 2048 + t * 8;
#pragma unroll
      for (int e = 0; e < 8; ++e) m[e] = p[e] != 0;
    } else {
      const int* p = mi + b * 2048 + t * 8;
#pragma unroll
      for (int e = 0; e < 8; ++e) m[e] = p[e] != 0;
    }
    int local = 0;
#pragma unroll
    for (int e = 0; e < 8; ++e) local += m[e];
    s[t] = local;
    __syncthreads();
    for (int off = 1; off < 256; off <<= 1) {
      int v = (t >= off) ? s[t - off] : 0;
      __syncthreads();
      s[t] += v;
      __syncthreads();
    }
    int offp = s[t] - local;
#pragma unroll
    for (int e = 0; e < 8; ++e)
      if (m[e]) sel[b * 2048 + offp++] = t * 8 + e;
    if (t == 0) {
      counts[b] = s[255];
      npad[b] = ((s[255] + 127) >> 7) << 7;
    }
  }
}

// ---------------------------------------------------------------- L2 gather
__global__ LB256 void gather_x(const f16* __restrict__ xh, const int* __restrict__ sel,
                               const int* __restrict__ counts,
                               const int* __restrict__ npad, f16* __restrict__ xc) {
  const int b = blockIdx.y;
  const int np = npad[b], cnt = counts[b];
  const int t = threadIdx.x;
#pragma unroll
  for (int i = 0; i < 4; ++i) {
    const int sp = blockIdx.x * 4 + i;
    if (sp >= np) continue;
    f16* dst = xc + ((long)b * 2048 + sp) * 1024;
    if (sp >= cnt) {
      *(f16x4*)(dst + t * 4) = (f16x4){0, 0, 0, 0};
    } else {
      const f16* src = xh + ((long)b * 2048 + sel[b * 2048 + sp]) * 1024;
      *(f16x4*)(dst + t * 4) = *(const f16x4*)(src + t * 4);
    }
  }
}

// ---------------------------------------------------------------- L3 Q+K+Vt (XCD-grouped)
// Q tiles [0,512): id = n*64 + m -> the 8 n-tiles sharing A-rows m have ids = m
// (mod 8) -> same XCD L2. K/Vt: per-batch row-tiles flattened to r in [0,rowsK),
// padded to MTp (mult of 8); K id = 512 + n*MTp + r; Vt id = base2 + m*MTp + r.
__global__ __launch_bounds__(256, 4) void qkvt_gemm(
    const f16* __restrict__ xh, const f16* __restrict__ xc,
    const f16* __restrict__ Wh, f16* __restrict__ Qb, f16* __restrict__ Kc,
    f16* __restrict__ Vt, const float* __restrict__ bq,
    const float* __restrict__ bk, const float* __restrict__ bv,
    const int* __restrict__ npad) {
  __shared__ __align__(16) f16 As[128 * 64];
  __shared__ __align__(16) f16 Bs[128 * 64];
  int cum[5];
  cum[0] = 0;
#pragma unroll
  for (int b = 0; b < 4; ++b) cum[b + 1] = cum[b] + (npad[b] >> 7);
  const int rowsK = cum[4];
  const int MTp = (rowsK + 7) & ~7;
  const int base2 = 512 + 8 * MTp;
  const int T = base2 + 8 * MTp;

  for (int tile = blockIdx.x; tile < T; tile += gridDim.x) {
    if (tile < 512) {
      const int m = tile & 63, n = tile >> 6;
      gemm_body<f16>(As, Bs, xh, 1024, Wh, 1024, Qb, 1024, bq, bq, 1 << 30, 0,
                     1.0f, 1024, m * 128, n * 128);
    } else if (tile < base2) {
      const int u = tile - 512;
      const int n = u / MTp, r = u % MTp;
      if (r >= rowsK) continue;
      int b = 0;
      while (r >= cum[b + 1]) ++b;
      const int m = r - cum[b];
      gemm_body<f16>(As, Bs, xc + (long)b * 2048 * 1024, 1024, Wh + 1048576, 1024,
                     Kc + (long)b * 2048 * 1024, 1024, bk, bk, 1 << 30, 0, 1.0f,
                     1024, m * 128, n * 128);
    } else {
      const int u = tile - base2;
      const int m = u / MTp, r = u % MTp;
      if (r >= rowsK) continue;
      int b = 0;
      while (r >= cum[b + 1]) ++b;
      const int n = r - cum[b];
      gemm_body<f16>(As, Bs, Wh + 2097152, 1024, xc + (long)b * 2048 * 1024, 1024,
                     Vt + (long)b * 1024 * 2048, 2048, bv, bv, 0, 1, 1.0f, 1024,
                     m * 128, n * 128);
    }
  }
}

// ---------------------------------------------------------------- L4 S GEMM (128x128)
// Group by shared Kc panel (each Kc n-tile is read by 16 m-tiles): flatten (b,n)
// to rn in [0,rowsN), pad to Np (mult of 8); id = m*Np + rn -> same rn same XCD.
__global__ __launch_bounds__(256, 4) void s_gemm128(
    const f16* __restrict__ Qb, const f16* __restrict__ Kc, f16* __restrict__ Sbuf,
    const int* __restrict__ npad) {
  __shared__ __align__(16) f16 As[128 * 64];
  __shared__ __align__(16) f16 Bs[128 * 64];
  int cum[5];
  cum[0] = 0;
#pragma unroll
  for (int b = 0; b < 4; ++b) cum[b + 1] = cum[b] + (npad[b] >> 7);
  const int rowsN = cum[4];
  const int Np = (rowsN + 7) & ~7;
  const int T = 16 * Np;

  for (int tile = blockIdx.x; tile < T; tile += gridDim.x) {
    const int m = tile / Np, rn = tile % Np;
    if (rn >= rowsN) continue;
    int b = 0;
    while (rn >= cum[b + 1]) ++b;
    const int n = rn - cum[b];
    gemm_body<f16>(As, Bs, Qb + (long)b * 2048 * 1024, 1024,
                   Kc + (long)b * 2048 * 1024, 1024,
                   Sbuf + (long)b * 2048 * 2048, 2048, nullptr, nullptr, 0, 0,
                   0.03125f, 1024, m * 128, n * 128);
  }
}

// ---------------------------------------------------------------- L5 softmax (wave-per-row)
__global__ LB256 void softmax_w(f16* __restrict__ S, const int* __restrict__ counts,
                                const int* __restrict__ npad) {
  const int wv = threadIdx.x >> 6, l = threadIdx.x & 63;
  const long r = (long)blockIdx.x * 4 + wv;
  const int b = (int)(r >> 11);
  const int nv = counts[b], np = npad[b];
  f16* row = S + r * 2048;

  float v[4][8];
  bool have[4];
  float mx = -3.0e38f;
#pragma unroll
  for (int g = 0; g < 4; ++g) {
    const int idx = (g * 64 + l) * 8;
    have[g] = idx < np;
    if (have[g]) {
      f16x8 sv = *(const f16x8*)(row + idx);
#pragma unroll
      for (int e = 0; e < 8; ++e) {
        float s = (idx + e < nv) ? (float)sv[e] : -3.0e38f;
        v[g][e] = s;
        mx = fmaxf(mx, s);
      }
    } else {
#pragma unroll
      for (int e = 0; e < 8; ++e) v[g][e] = -3.0e38f;
    }
  }
#pragma unroll
  for (int off = 32; off > 0; off >>= 1) mx = fmaxf(mx, __shfl_xor(mx, off, 64));

  float sum = 0.f;
  float ev[4][8];
#pragma unroll
  for (int g = 0; g < 4; ++g)
#pragma unroll
    for (int e = 0; e < 8; ++e) {
      float t = (v[g][e] <= -1.0e38f) ? 0.f : __expf(v[g][e] - mx);
      ev[g][e] = t;
      sum += t;
    }
#pragma unroll
  for (int off = 32; off > 0; off >>= 1) sum += __shfl_xor(sum, off, 64);
  const float inv = 1.f / sum;
#pragma unroll
  for (int g = 0; g < 4; ++g) {
    if (!have[g]) continue;
    const int idx = (g * 64 + l) * 8;
    f16x8 ov;
#pragma unroll
    for (int e = 0; e < 8; ++e) ov[e] = (f16)(ev[g][e] * inv);
    *(f16x8*)(row + idx) = ov;
  }
}

// ---------------------------------------------------------------- L6 PV GEMM (128x128)
// O = P @ Vt^T (K=npad). rm = b*16+m in [0,64); id = n*64 + rm: the 8 n-tiles
// sharing Sbuf rows (b,m) have ids = rm (mod 8) -> same XCD. T = 512 exact.
__global__ __launch_bounds__(256, 4) void pv_gemm128(
    const f16* __restrict__ Sbuf, const f16* __restrict__ Vt,
    float* __restrict__ out, const int* __restrict__ npad) {
  __shared__ __align__(16) f16 As[128 * 64];
  __shared__ __align__(16) f16 Bs[128 * 64];
  const int tile = blockIdx.x;
  const int n = tile >> 6, rm = tile & 63, b = rm >> 4, m = rm & 15;
  gemm_body<float>(As, Bs, Sbuf + (long)b * 2048 * 2048, 2048,
                   Vt + (long)b * 1024 * 2048, 2048, out + (long)b * 2048 * 1024,
                   1024, nullptr, nullptr, 0, 0, 1.0f, npad[b], m * 128, n * 128);
}

// ---------------------------------------------------------------- launch
extern "C" void kernel_launch(void* const* d_in, const int* in_sizes, int n_in,
                              void* d_out, int out_size, void* d_ws, size_t ws_size,
                              hipStream_t stream) {
  const float* x = (const float*)d_in[0];
  const void* mask = d_in[1];
  const float* Wq = (const float*)d_in[2];
  const float* bq = (const float*)d_in[3];
  const float* Wk = (const float*)d_in[4];
  const float* bk = (const float*)d_in[5];
  const float* Wv = (const float*)d_in[6];
  const float* bv = (const float*)d_in[7];
  float* out = (float*)d_out;

  // Workspace (f16 elems), 118 MB total (proven available in R1).
  f16* xh = (f16*)d_ws;              // 8M  [0,16MB)
  f16* xc = xh + 8388608;            // 8M  [16,32)
  f16* Wh = xc + 8388608;            // 3M  [32,38)  [Wq|Wk|Wv]
  f16* Qb = Wh + 3145728;            // 8M  [38,54)
  f16* Kc = Qb + 8388608;            // 8M  [54,70)
  f16* Vt = Kc + 8388608;            // 8M  [70,86)
  f16* Sbuf = Vt + 8388608;          // 16M [86,118)
  int* sel = (int*)(Sbuf + 16777216);
  int* counts = sel + 8192;
  int* npad = counts + 4;

  prep<<<2052, 256, 0, stream>>>(x, Wq, Wk, Wv, mask, xh, Wh, sel, counts, npad);
  gather_x<<<dim3(512, 4), 256, 0, stream>>>(xh, sel, counts, npad, xc);
  qkvt_gemm<<<1024, 256, 0, stream>>>(xh, xc, Wh, Qb, Kc, Vt, bq, bk, bv, npad);
  s_gemm128<<<1024, 256, 0, stream>>>(Qb, Kc, Sbuf, npad);
  softmax_w<<<2048, 256, 0, stream>>>(Sbuf, counts, npad);
  pv_gemm128<<<512, 256, 0, stream>>>(Sbuf, Vt, out, npad);
}